// Round 12
// baseline (206.419 us; speedup 1.0000x reference)
//
#include <hip/hip_runtime.h>
#include <hip/hip_bf16.h>

#define N_ATOMS 32768

typedef __attribute__((ext_vector_type(4))) float f32x4;
typedef __attribute__((ext_vector_type(8))) short bf16x8;
typedef unsigned short u16;

__device__ __forceinline__ u16 f2b(float f) {
    union { __hip_bfloat16 b; u16 u; } c;
    c.b = __float2bfloat16(f);
    return c.u;
}
__device__ __forceinline__ float b2f(u16 u) {
    union { unsigned int i; float f; } c;
    c.i = ((unsigned int)u) << 16;
    return c.f;
}

#define GLDS16(src, dst) __builtin_amdgcn_global_load_lds( \
    (const __attribute__((address_space(1))) void*)(src),  \
    (__attribute__((address_space(3))) void*)(dst), 16, 0, 0)

// ---------------- merged setup kernel: convx + convw + zero(out_inv) ----------------
__global__ void __launch_bounds__(256) setup_kernel(
        const float* __restrict__ x, u16* __restrict__ xhi, u16* __restrict__ xlo,
        const float* __restrict__ w1l, const float* __restrict__ w2l,
        const float* __restrict__ w3l, const float* __restrict__ w1r,
        const float* __restrict__ w2r,
        u16* __restrict__ W1LThi, u16* __restrict__ W1LTlo, u16* __restrict__ W1RT,
        u16* __restrict__ W2LThi, u16* __restrict__ W2LTlo, u16* __restrict__ W2RT,
        u16* __restrict__ W3LThi, u16* __restrict__ W3LTlo,
        float* __restrict__ out_inv) {
    int bid = blockIdx.x;
    if (bid < 4096) {
        size_t i = (size_t)(bid * 256 + threadIdx.x) * 8;
        float4 v0 = *(const float4*)(x + i);
        float4 v1 = *(const float4*)(x + i + 4);
        float v[8] = {v0.x, v0.y, v0.z, v0.w, v1.x, v1.y, v1.z, v1.w};
        bf16x8 rh, rl;
#pragma unroll
        for (int j = 0; j < 8; ++j) {
            u16 h = f2b(v[j]);
            rh[j] = (short)h;
            rl[j] = (short)f2b(v[j] - b2f(h));
        }
        *(bf16x8*)(xhi + i) = rh;
        *(bf16x8*)(xlo + i) = rl;
    } else if (bid < 7424) {
        int i = (bid - 4096) * 256 + threadIdx.x;
        if (i < 131072) {                       // w1_lat -> [512][256] hi/lo
            int n = i >> 8, k = i & 255;
            float v = w1l[k * 512 + n];
            u16 h = f2b(v);
            W1LThi[i] = h;
            W1LTlo[i] = f2b(v - b2f(h));
        } else if (i < 262144) {                // w1_ro -> [512][256] bf16
            int j = i - 131072;
            int n = j >> 8, k = j & 255;
            W1RT[j] = f2b(w1r[k * 512 + n]);
        } else if (i < 524288) {                // w2_lat -> [512][512] hi/lo
            int j = i - 262144;
            int n = j >> 9, k = j & 511;
            float v = w2l[k * 512 + n];
            u16 h = f2b(v);
            W2LThi[j] = h;
            W2LTlo[j] = f2b(v - b2f(h));
        } else if (i < 786432) {                // w2_ro -> bf16
            int j = i - 524288;
            int n = j >> 9, k = j & 511;
            W2RT[j] = f2b(w2r[k * 512 + n]);
        } else if (i < 851968) {                // w3_lat -> [128][512] hi/lo
            int j = i - 786432;
            int n = j >> 9, k = j & 511;
            float v = w3l[k * 128 + n];
            u16 h = f2b(v);
            W3LThi[j] = h;
            W3LTlo[j] = f2b(v - b2f(h));
        }
    } else {
        int i = (bid - 7424) * 256 + threadIdx.x;
        *(float4*)(out_inv + i * 4) = float4{0.f, 0.f, 0.f, 0.f};
    }
}

// ---------------- gemm8x: m201-anatomy 4-phase split-bf16 GEMM (lat branch) --------
// C = silu( scale * (Ahi@Bhi^T + Alo@Bhi^T + Ahi@Blo^T) ), split hi/lo bf16 out.
// BM=BN=256, BK=64, 512 threads = 8 waves (2M x 4N), per-wave 128x64 (acc[8][4]).
// LDS 128KB: A,B each [2 buf][2 half(128 rows)][128x64 u16].  Per K-tile, 4 phases
// (mh,kk)=(0,0),(1,0),(0,1),(1,1), each: {8-or-4 ds_read_b128 -> stage 1 half-tile
// of t+1 -> barrier -> lgkmcnt(0)+sched_barrier -> setprio(1) 16 MFMA setprio(0)
// -> barrier}.  Halves staged in order [A0,A1,B0,B1]: HBM-latency A gets 2.5-3.5
// phases of cover, L2-resident B 0.5-1.5.  ONE vmcnt(0) per tile at the boundary
// (all of t+1's loads already 1-4 phases old -> ~0 stall; not a mid-issue drain).
// Waves release staggered from the pre-MFMA barrier via per-wave lgkmcnt ->
// LDS pipe serves wave w+1's reads under wave w's MFMA cluster (m201 mechanism).
template<int GX>
__global__ void __launch_bounds__(512, 1) gemm8x(
        const u16* __restrict__ Ahi, const u16* __restrict__ Alo,
        const u16* __restrict__ Bhi, const u16* __restrict__ Blo,
        u16* __restrict__ Chi, u16* __restrict__ Clo,
        int ldc, int K, float scale) {
    __shared__ __align__(16) u16 smem[65536];   // A: [0,32768), B: [32768,65536)
    const int tid = threadIdx.x;
    const int lane = tid & 63;
    const int wid = tid >> 6;
    const int wm = wid >> 2;            // A-half this wave reads
    const int wn = wid & 3;             // B 64-row quarter
    const int bh = wn >> 1;             // B-half this wave reads
    const int br0 = (wn & 1) * 64;      // local row base within B-half
    const int rlane = lane & 15;
    const int kc = lane >> 4;           // 0..3
    const int cps = rlane & 7;          // local_row & 7 for all fragment rows
    const int srow = tid >> 3;          // 0..63 staging row
    const int scp = tid & 7;            // staging chunk

    const int nwg = gridDim.x;
    const int bid = blockIdx.x;
    const int wg = (bid & 7) * (nwg >> 3) + (bid >> 3);
    const int bn = (wg % GX) * 256;
    const int bm = (wg / GX) * 256;

    const int kt = K >> 6;
    const int NT = 3 * kt;

    // stage one half-tile (2 gload_lds/thread): mat 0=A 1=B, half h, tile t -> buf t&1
    auto stage = [&](int t, int mat, int h) {
        int seg = (t >= kt) + (t >= 2 * kt);
        int k0 = (t - seg * kt) << 6;
        int buf = t & 1;
        const u16* src = (mat == 0) ? ((seg == 1) ? Alo : Ahi)
                                    : ((seg == 2) ? Blo : Bhi);
        int grow = ((mat == 0) ? bm : bn) + h * 128;
        u16* dst = smem + mat * 32768 + buf * 16384 + h * 8192;
#pragma unroll
        for (int call = 0; call < 2; ++call) {
            int row = call * 64 + srow;
            int c = scp ^ (row & 7);    // pre-swizzled source, linear LDS dest (tid*16B)
            GLDS16(src + (size_t)(grow + row) * K + k0 + c * 8, dst + row * 64 + scp * 8);
        }
    };

    f32x4 acc[8][4] = {};
    bf16x8 af[4], bf[4];

#define RD_B(buf, kk) do {                                                     \
        const u16* lb_ = smem + 32768 + (buf) * 16384 + bh * 8192;             \
        _Pragma("unroll")                                                      \
        for (int n_ = 0; n_ < 4; ++n_) {                                       \
            int row_ = br0 + n_ * 16 + rlane;                                  \
            bf[n_] = *(const bf16x8*)&lb_[row_ * 64 + (((kk) * 4 + kc) ^ cps) * 8]; \
        }                                                                      \
    } while (0)
#define RD_A(buf, mh, kk) do {                                                 \
        const u16* la_ = smem + (buf) * 16384 + wm * 8192;                     \
        _Pragma("unroll")                                                      \
        for (int m_ = 0; m_ < 4; ++m_) {                                       \
            int row_ = (mh) * 64 + m_ * 16 + rlane;                            \
            af[m_] = *(const bf16x8*)&la_[row_ * 64 + (((kk) * 4 + kc) ^ cps) * 8]; \
        }                                                                      \
    } while (0)
#define MM(mh) do {                                                            \
        asm volatile("s_waitcnt lgkmcnt(0)" ::: "memory");                     \
        __builtin_amdgcn_sched_barrier(0);                                     \
        __builtin_amdgcn_s_setprio(1);                                         \
        _Pragma("unroll")                                                      \
        for (int m_ = 0; m_ < 4; ++m_)                                         \
            _Pragma("unroll")                                                  \
            for (int n_ = 0; n_ < 4; ++n_)                                     \
                acc[(mh) * 4 + m_][n_] = __builtin_amdgcn_mfma_f32_16x16x32_bf16( \
                    af[m_], bf[n_], acc[(mh) * 4 + m_][n_], 0, 0, 0);          \
        __builtin_amdgcn_s_setprio(0);                                         \
    } while (0)
#define BAR __builtin_amdgcn_s_barrier()

    // prologue: tile 0's 4 halves; all landed before first reads
    stage(0, 0, 0); stage(0, 0, 1); stage(0, 1, 0); stage(0, 1, 1);
    asm volatile("s_waitcnt vmcnt(0)" ::: "memory");
    BAR;

    for (int t = 0; t < NT; ++t) {
        const int buf = t & 1;
        const bool pf = (t + 1 < NT);
        // phase 0: (mh0,kk0) | stage A-half0(t+1)  [obuf free: t-1 readers retired]
        RD_B(buf, 0); RD_A(buf, 0, 0);
        if (pf) stage(t + 1, 0, 0);
        BAR; MM(0); BAR;
        // phase 1: (mh1,kk0) | stage A-half1(t+1)
        RD_A(buf, 1, 0);
        if (pf) stage(t + 1, 0, 1);
        BAR; MM(1); BAR;
        // phase 2: (mh0,kk1) | stage B-half0(t+1)
        RD_B(buf, 1); RD_A(buf, 0, 1);
        if (pf) stage(t + 1, 1, 0);
        BAR; MM(0); BAR;
        // phase 3: (mh1,kk1) | stage B-half1(t+1)
        RD_A(buf, 1, 1);
        if (pf) stage(t + 1, 1, 1);
        BAR; MM(1);
        // tile boundary: t+1's 4 halves (issued 1-4 phases ago) landed; gate buf reuse
        asm volatile("s_waitcnt vmcnt(0)" ::: "memory");
        BAR;
    }
#undef BAR
#undef MM
#undef RD_A
#undef RD_B

    // epilogue: split hi/lo bf16; C/D layout col = lane&15, row = (lane>>4)*4 + reg
    const int g = lane >> 4;
#pragma unroll
    for (int m = 0; m < 8; ++m) {
        int grow0 = bm + wm * 128 + m * 16 + (g << 2);
#pragma unroll
        for (int n = 0; n < 4; ++n) {
            int gcol = bn + wn * 64 + n * 16 + rlane;
#pragma unroll
            for (int r = 0; r < 4; ++r) {
                float v = acc[m][n][r] * scale;
                v = v / (1.0f + __expf(-v));
                size_t idx = (size_t)(grow0 + r) * ldc + gcol;
                u16 h = f2b(v);
                Chi[idx] = h;
                Clo[idx] = f2b(v - b2f(h));
            }
        }
    }
}

// ---------------- 256-row 8-wave MFMA GEMM (R4/R7/R9-proven schedule) ----------------
// OUTK: 0 = f32, 1 = bf16, 3 = fused invout (dot w3_ro -> atomicAdd e_out).
template<int NSEG, int GX, int NF, bool SILU, int OUTK>
__global__ void __launch_bounds__(512, 2) gemm8p(
        const u16* __restrict__ Ahi, const u16* __restrict__ Alo,
        const u16* __restrict__ Bhi, const u16* __restrict__ Blo,
        void* __restrict__ Chi, void* __restrict__ Clo,
        int ldc, int K, float scale,
        const float* __restrict__ e_w3, float* __restrict__ e_out) {
    constexpr int LBSZ = NF * 64 * 64;
    constexpr int SMEMN = 32768 + 2 * LBSZ;
    __shared__ __align__(16) u16 smem[SMEMN];
    u16* const lA0 = smem;
    u16* const lB0 = smem + 32768;
    const int tid = threadIdx.x;
    const int lane = tid & 63;
    const int wid = tid >> 6;
    const int wm = wid >> 2;
    const int wn = wid & 3;
    const int rlane = lane & 15;
    const int kc = lane >> 4;
    const int cps = rlane & 7;
    const int srow = tid >> 3;
    const int scp = tid & 7;

    const int nwg = gridDim.x;
    const int bid = blockIdx.x;
    const int wg = (bid & 7) * (nwg >> 3) + (bid >> 3);
    const int bn = (wg % GX) * (NF * 64);
    const int bm = (wg / GX) * 256;

    const int kt = K >> 6;
    const int NT = NSEG * kt;

    auto stageA = [&](int t, int buf) {
        int seg = (NSEG == 1) ? 0 : ((t >= kt) + (t >= 2 * kt));
        const u16* As = (NSEG == 1) ? Ahi : (seg == 1 ? Alo : Ahi);
        int k0 = (t - seg * kt) << 6;
        u16* la = lA0 + buf * 16384;
#pragma unroll
        for (int call = 0; call < 4; ++call) {
            int row = call * 64 + srow;
            int c = scp ^ (row & 7);
            GLDS16(As + (size_t)(bm + row) * K + k0 + c * 8, la + (size_t)(row * 64 + scp * 8));
        }
    };
    auto stageB = [&](int t, int buf) {
        int seg = (NSEG == 1) ? 0 : ((t >= kt) + (t >= 2 * kt));
        const u16* Bs = (NSEG == 1) ? Bhi : (seg == 2 ? Blo : Bhi);
        int k0 = (t - seg * kt) << 6;
        u16* lb = lB0 + buf * LBSZ;
#pragma unroll
        for (int call = 0; call < NF; ++call) {
            int row = call * 64 + srow;
            int c = scp ^ (row & 7);
            GLDS16(Bs + (size_t)(bn + row) * K + k0 + c * 8, lb + (size_t)(row * 64 + scp * 8));
        }
    };

    f32x4 acc[8][NF] = {};

    stageA(0, 0);
    stageB(0, 0);
    asm volatile("s_waitcnt vmcnt(0)" ::: "memory");
    __builtin_amdgcn_s_barrier();

    for (int t = 0; t < NT; ++t) {
        const int cur = t & 1, nxt = cur ^ 1;
        const bool pf = (t + 1 < NT);
        const u16* la = lA0 + cur * 16384;
        const u16* lb = lB0 + cur * LBSZ;
#pragma unroll
        for (int ks = 0; ks < 2; ++ks) {
            bf16x8 af[8], bfr[NF];
            const int cp = (ks * 4 + kc) ^ cps;
#pragma unroll
            for (int m = 0; m < 8; ++m) {
                int row = wm * 128 + m * 16 + rlane;
                af[m] = *(const bf16x8*)&la[row * 64 + cp * 8];
            }
#pragma unroll
            for (int n = 0; n < NF; ++n) {
                int row = wn * (NF * 16) + n * 16 + rlane;
                bfr[n] = *(const bf16x8*)&lb[row * 64 + cp * 8];
            }
            if (pf) {
                if (ks == 0) stageA(t + 1, nxt);
                else         stageB(t + 1, nxt);
            }
            asm volatile("s_waitcnt lgkmcnt(0)" ::: "memory");
            __builtin_amdgcn_sched_barrier(0);
            __builtin_amdgcn_s_setprio(1);
#pragma unroll
            for (int m = 0; m < 8; ++m)
#pragma unroll
                for (int n = 0; n < NF; ++n)
                    acc[m][n] = __builtin_amdgcn_mfma_f32_16x16x32_bf16(af[m], bfr[n], acc[m][n], 0, 0, 0);
            __builtin_amdgcn_s_setprio(0);
        }
        asm volatile("s_waitcnt vmcnt(0)" ::: "memory");
        __builtin_amdgcn_s_barrier();
    }

    const int g = lane >> 4;

    if constexpr (OUTK == 3) {
        const float s512f = 0.04419417382415922f;
        float wj0[NF], wj1[NF];
#pragma unroll
        for (int n = 0; n < NF; ++n) {
            int gc = bn + wn * (NF * 16) + n * 16 + rlane;
            wj0[n] = e_w3[gc * 2] * s512f;
            wj1[n] = e_w3[gc * 2 + 1] * s512f;
        }
#pragma unroll
        for (int m = 0; m < 8; ++m)
#pragma unroll
            for (int r = 0; r < 4; ++r) {
                float s0 = 0.f, s1 = 0.f;
#pragma unroll
                for (int n = 0; n < NF; ++n) {
                    float v = acc[m][n][r] * scale;
                    v = v / (1.0f + __expf(-v));
                    s0 = fmaf(v, wj0[n], s0);
                    s1 = fmaf(v, wj1[n], s1);
                }
#pragma unroll
                for (int off = 1; off < 16; off <<= 1) {
                    s0 += __shfl_xor(s0, off);
                    s1 += __shfl_xor(s1, off);
                }
                if (rlane == 0) {
                    int row = bm + wm * 128 + m * 16 + g * 4 + r;
                    atomicAdd(&e_out[row * 2], s0);
                    atomicAdd(&e_out[row * 2 + 1], s1);
                }
            }
    } else {
#pragma unroll
        for (int m = 0; m < 8; ++m) {
            int grow0 = bm + wm * 128 + m * 16 + (g << 2);
#pragma unroll
            for (int n = 0; n < NF; ++n) {
                int gcol = bn + wn * (NF * 16) + n * 16 + rlane;
#pragma unroll
                for (int r = 0; r < 4; ++r) {
                    float v = acc[m][n][r] * scale;
                    if constexpr (SILU) v = v / (1.0f + __expf(-v));
                    size_t idx = (size_t)(grow0 + r) * ldc + gcol;
                    if constexpr (OUTK == 0) ((float*)Chi)[idx] = v;
                    else                     ((u16*)Chi)[idx] = f2b(v);
                }
            }
        }
    }
}

// ---------------- per-atom equivariant output (R2-verified) ----------------
__global__ void eq_kernel(const float* __restrict__ eqf, const float* __restrict__ wgt,
                          const int* __restrict__ types, const float* __restrict__ bond,
                          float* __restrict__ out) {
    int t = blockIdx.x * 256 + threadIdx.x;
    int n = t >> 2, v = t & 3;
    const float* e = eqf + (size_t)n * 96;
    const float* w = wgt + (size_t)n * 128 + v;
    float a0 = 0.f, a1 = 0.f, a2 = 0.f;
#pragma unroll
    for (int u = 0; u < 32; ++u) {
        float wv = w[u * 4];
        a0 = fmaf(e[u * 3 + 0], wv, a0);
        a1 = fmaf(e[u * 3 + 1], wv, a1);
        a2 = fmaf(e[u * 3 + 2], wv, a2);
    }
    const float s = 0.17677669529663687f;
    a0 *= s; a1 *= s; a2 *= s;
    float norm = sqrtf(a0 * a0 + a1 * a1 + a2 * a2) + 1e-10f;
    float bl = bond[types[n] * 4 + v];
    float r0 = a0 / norm, r1 = a1 / norm, r2 = a2 / norm;
    if (isnan(r0)) r0 = 0.f;
    if (isnan(r1)) r1 = 0.f;
    if (isnan(r2)) r2 = 0.f;
    out[(size_t)n * 12 + v * 3 + 0] = r0 * bl;
    out[(size_t)n * 12 + v * 3 + 1] = r1 * bl;
    out[(size_t)n * 12 + v * 3 + 2] = r2 * bl;
}

// ---------------- launcher ----------------
extern "C" void kernel_launch(void* const* d_in, const int* in_sizes, int n_in,
                              void* d_out, int out_size, void* d_ws, size_t ws_size,
                              hipStream_t stream) {
    const float* inv  = (const float*)d_in[0];
    const float* eqf  = (const float*)d_in[1];
    const int*   typs = (const int*)d_in[2];
    const float* w1l  = (const float*)d_in[3];
    const float* w2l  = (const float*)d_in[4];
    const float* w3l  = (const float*)d_in[5];
    const float* w1r  = (const float*)d_in[6];
    const float* w2r  = (const float*)d_in[7];
    const float* w3r  = (const float*)d_in[8];
    const float* bond = (const float*)d_in[9];

    char* ws = (char*)d_ws;
    const size_t MB = 1024 * 1024, KB = 1024;
    u16* XHI   = (u16*)(ws);             // 16MB, dead after ro-L1
    u16* XLO   = (u16*)(ws + 16 * MB);   // 16MB, dead after lat-L1
    u16* H1R   = (u16*)(ws + 32 * MB);   // 32MB, dead after ro-L2f
    u16* H1Lhi = (u16*)(ws + 64 * MB);   // 32MB, dead after lat-L2
    u16* H1Llo = (u16*)(ws + 96 * MB);   // 32MB, dead after lat-L2
    u16* H2Lhi = (u16*)(ws);             // 32MB, over XHI+XLO (dead)
    u16* H2Llo = (u16*)(ws + 128 * MB);  // 32MB fresh
    float* WGT = (float*)(ws + 32 * MB); // 16MB, over H1R (dead)
    char* wb = ws + 160 * MB;
    u16* W1LThi = (u16*)(wb);
    u16* W1LTlo = (u16*)(wb + 256 * KB);
    u16* W1RT   = (u16*)(wb + 512 * KB);
    u16* W2LThi = (u16*)(wb + 768 * KB);
    u16* W2LTlo = (u16*)(wb + 1280 * KB);
    u16* W2RT   = (u16*)(wb + 1792 * KB);
    u16* W3LThi = (u16*)(wb + 2304 * KB);
    u16* W3LTlo = (u16*)(wb + 2432 * KB);

    float* out_inv = (float*)d_out;                 // [32768][2]
    float* out_eq  = (float*)d_out + N_ATOMS * 2;   // [32768][4][3]

    const float s256 = 0.0625f;                 // 1/sqrt(256)
    const float s512 = 0.04419417382415922f;    // 1/sqrt(512)

    // 1. setup: convx + convw + zero(out_inv)
    setup_kernel<<<dim3(7488), dim3(256), 0, stream>>>(
        inv, XHI, XLO, w1l, w2l, w3l, w1r, w2r,
        W1LThi, W1LTlo, W1RT, W2LThi, W2LTlo, W2RT, W3LThi, W3LTlo, out_inv);
    // 2. lat L1 (gemm8x, m201-anatomy): -> H1L hi/lo
    gemm8x<2><<<dim3(256), dim3(512), 0, stream>>>(
        XHI, XLO, W1LThi, W1LTlo, H1Lhi, H1Llo, 512, 256, s256);
    // 3. ro L1 (proven gemm8p): -> H1R
    gemm8p<1, 2, 4, true, 1><<<dim3(256), dim3(512), 0, stream>>>(
        XHI, nullptr, W1RT, nullptr, H1R, nullptr, 512, 256, s256, nullptr, nullptr);
    // 4. ro L2 + invout fused (proven gemm8p): atomics into out_inv
    gemm8p<1, 2, 4, true, 3><<<dim3(256), dim3(512), 0, stream>>>(
        H1R, nullptr, W2RT, nullptr, nullptr, nullptr, 0, 512, s512, w3r, out_inv);
    // 5. lat L2 (gemm8x): -> H2L hi/lo   [after ro dispatches: H2Lhi over dead XHI/XLO]
    gemm8x<2><<<dim3(256), dim3(512), 0, stream>>>(
        H1Lhi, H1Llo, W2LThi, W2LTlo, H2Lhi, H2Llo, 512, 512, s512);
    // 6. lat L3 (proven gemm8p, NF=1, full GPU): -> WGT f32
    gemm8p<3, 2, 1, false, 0><<<dim3(256), dim3(512), 0, stream>>>(
        H2Lhi, H2Llo, W3LThi, W3LTlo, WGT, nullptr, 128, 512, s512, nullptr, nullptr);
    // 7. equivariant epilogue
    eq_kernel<<<dim3(512), dim3(256), 0, stream>>>(eqf, WGT, typs, bond, out_eq);
}

// Round 13
// 195.900 us; speedup vs baseline: 1.0537x; 1.0537x over previous
//
#include <hip/hip_runtime.h>
#include <hip/hip_bf16.h>

#define N_ATOMS 32768

typedef __attribute__((ext_vector_type(4))) float f32x4;
typedef __attribute__((ext_vector_type(8))) short bf16x8;
typedef unsigned short u16;

__device__ __forceinline__ u16 f2b(float f) {
    union { __hip_bfloat16 b; u16 u; } c;
    c.b = __float2bfloat16(f);
    return c.u;
}
__device__ __forceinline__ float b2f(u16 u) {
    union { unsigned int i; float f; } c;
    c.i = ((unsigned int)u) << 16;
    return c.f;
}

#define GLDS16(src, dst) __builtin_amdgcn_global_load_lds( \
    (const __attribute__((address_space(1))) void*)(src),  \
    (__attribute__((address_space(3))) void*)(dst), 16, 0, 0)

// ---------------- merged setup kernel: convx + convw + zero(out_inv) ----------------
__global__ void __launch_bounds__(256) setup_kernel(
        const float* __restrict__ x, u16* __restrict__ xhi, u16* __restrict__ xlo,
        const float* __restrict__ w1l, const float* __restrict__ w2l,
        const float* __restrict__ w3l, const float* __restrict__ w1r,
        const float* __restrict__ w2r,
        u16* __restrict__ W1LThi, u16* __restrict__ W1LTlo, u16* __restrict__ W1RT,
        u16* __restrict__ W2LThi, u16* __restrict__ W2LTlo, u16* __restrict__ W2RT,
        u16* __restrict__ W3LThi, u16* __restrict__ W3LTlo,
        float* __restrict__ out_inv) {
    int bid = blockIdx.x;
    if (bid < 4096) {
        size_t i = (size_t)(bid * 256 + threadIdx.x) * 8;
        float4 v0 = *(const float4*)(x + i);
        float4 v1 = *(const float4*)(x + i + 4);
        float v[8] = {v0.x, v0.y, v0.z, v0.w, v1.x, v1.y, v1.z, v1.w};
        bf16x8 rh, rl;
#pragma unroll
        for (int j = 0; j < 8; ++j) {
            u16 h = f2b(v[j]);
            rh[j] = (short)h;
            rl[j] = (short)f2b(v[j] - b2f(h));
        }
        *(bf16x8*)(xhi + i) = rh;
        *(bf16x8*)(xlo + i) = rl;
    } else if (bid < 7424) {
        int i = (bid - 4096) * 256 + threadIdx.x;
        if (i < 131072) {                       // w1_lat -> [512][256] hi/lo
            int n = i >> 8, k = i & 255;
            float v = w1l[k * 512 + n];
            u16 h = f2b(v);
            W1LThi[i] = h;
            W1LTlo[i] = f2b(v - b2f(h));
        } else if (i < 262144) {                // w1_ro -> [512][256] bf16
            int j = i - 131072;
            int n = j >> 8, k = j & 255;
            W1RT[j] = f2b(w1r[k * 512 + n]);
        } else if (i < 524288) {                // w2_lat -> [512][512] hi/lo
            int j = i - 262144;
            int n = j >> 9, k = j & 511;
            float v = w2l[k * 512 + n];
            u16 h = f2b(v);
            W2LThi[j] = h;
            W2LTlo[j] = f2b(v - b2f(h));
        } else if (i < 786432) {                // w2_ro -> bf16
            int j = i - 524288;
            int n = j >> 9, k = j & 511;
            W2RT[j] = f2b(w2r[k * 512 + n]);
        } else if (i < 851968) {                // w3_lat -> [128][512] hi/lo
            int j = i - 786432;
            int n = j >> 9, k = j & 511;
            float v = w3l[k * 128 + n];
            u16 h = f2b(v);
            W3LThi[j] = h;
            W3LTlo[j] = f2b(v - b2f(h));
        }
    } else {
        int i = (bid - 7424) * 256 + threadIdx.x;
        *(float4*)(out_inv + i * 4) = float4{0.f, 0.f, 0.f, 0.f};
    }
}

// ---------------- 256-row 8-wave MFMA GEMM body (R4/R7/R9/R10-proven schedule) --------
// C = act( scale * sum_seg Aseg @ Bseg^T ).  BM=256, BN=NF*64, BK=64,
// 512 threads = 8 waves (2M x 4N), per-wave 128 x NF*16 output (acc[8][NF]).
// Per K-tile: 2 phases {ds_read frags | stage half of next tile | lgkmcnt(0)
// | setprio(1) MFMA setprio(0)}, then vmcnt(0)+barrier.
// NSEG=3: K-segments (Ahi,Bhi),(Alo,Bhi),(Ahi,Blo) = split-bf16 ~f32 precision.
// OUTK: 0 = f32, 1 = bf16, 2 = split hi/lo bf16,
//       3 = fused invout (dot w3_ro -> atomicAdd e_out, nothing else stored).
template<int NSEG, int NF, bool SILU, int OUTK>
__device__ __forceinline__ void gemm_body(
        u16* __restrict__ smem,
        const u16* __restrict__ Ahi, const u16* __restrict__ Alo,
        const u16* __restrict__ Bhi, const u16* __restrict__ Blo,
        void* __restrict__ Chi, void* __restrict__ Clo,
        int ldc, int K, float scale,
        const float* __restrict__ e_w3, float* __restrict__ e_out,
        int bid, int nwg, int GX) {
    constexpr int LBSZ = NF * 64 * 64;      // u16 per B buffer
    u16* const lA0 = smem;                  // 2 x 16384
    u16* const lB0 = smem + 32768;          // 2 x LBSZ
    const int tid = threadIdx.x;
    const int lane = tid & 63;
    const int wid = tid >> 6;
    const int wm = wid >> 2;            // 0..1 -> 128-row half
    const int wn = wid & 3;             // 0..3 -> NF*16-col quarter
    const int rlane = lane & 15;
    const int kc = lane >> 4;           // 0..3
    const int cps = rlane & 7;
    const int srow = tid >> 3;          // 0..63
    const int scp = tid & 7;

    // bijective XCD swizzle (nwg % 8 == 0)
    const int wg = (bid & 7) * (nwg >> 3) + (bid >> 3);
    const int bn = (wg % GX) * (NF * 64);
    const int bm = (wg / GX) * 256;

    const int kt = K >> 6;
    const int NT = NSEG * kt;

    auto stageA = [&](int t, int buf) {
        int seg = (NSEG == 1) ? 0 : ((t >= kt) + (t >= 2 * kt));
        const u16* As = (NSEG == 1) ? Ahi : (seg == 1 ? Alo : Ahi);
        int k0 = (t - seg * kt) << 6;
        u16* la = lA0 + buf * 16384;
#pragma unroll
        for (int call = 0; call < 4; ++call) {
            int row = call * 64 + srow;
            int c = scp ^ (row & 7);    // pre-swizzled global source, linear LDS dest
            GLDS16(As + (size_t)(bm + row) * K + k0 + c * 8, la + (size_t)(row * 64 + scp * 8));
        }
    };
    auto stageB = [&](int t, int buf) {
        int seg = (NSEG == 1) ? 0 : ((t >= kt) + (t >= 2 * kt));
        const u16* Bs = (NSEG == 1) ? Bhi : (seg == 2 ? Blo : Bhi);
        int k0 = (t - seg * kt) << 6;
        u16* lb = lB0 + buf * LBSZ;
#pragma unroll
        for (int call = 0; call < NF; ++call) {
            int row = call * 64 + srow;
            int c = scp ^ (row & 7);
            GLDS16(Bs + (size_t)(bn + row) * K + k0 + c * 8, lb + (size_t)(row * 64 + scp * 8));
        }
    };

    f32x4 acc[8][NF] = {};

    // prologue: tile 0 in flight, then sync
    stageA(0, 0);
    stageB(0, 0);
    asm volatile("s_waitcnt vmcnt(0)" ::: "memory");
    __builtin_amdgcn_s_barrier();

    for (int t = 0; t < NT; ++t) {
        const int cur = t & 1, nxt = cur ^ 1;
        const bool pf = (t + 1 < NT);
        const u16* la = lA0 + cur * 16384;
        const u16* lb = lB0 + cur * LBSZ;
#pragma unroll
        for (int ks = 0; ks < 2; ++ks) {
            bf16x8 af[8], bfr[NF];
            const int cp = (ks * 4 + kc) ^ cps;
#pragma unroll
            for (int m = 0; m < 8; ++m) {
                int row = wm * 128 + m * 16 + rlane;
                af[m] = *(const bf16x8*)&la[row * 64 + cp * 8];
            }
#pragma unroll
            for (int n = 0; n < NF; ++n) {
                int row = wn * (NF * 16) + n * 16 + rlane;
                bfr[n] = *(const bf16x8*)&lb[row * 64 + cp * 8];
            }
            if (pf) {                       // issue next tile's loads early (stay in flight)
                if (ks == 0) stageA(t + 1, nxt);
                else         stageB(t + 1, nxt);
            }
            asm volatile("s_waitcnt lgkmcnt(0)" ::: "memory");
            __builtin_amdgcn_sched_barrier(0);
            __builtin_amdgcn_s_setprio(1);
#pragma unroll
            for (int m = 0; m < 8; ++m)
#pragma unroll
                for (int n = 0; n < NF; ++n)
                    acc[m][n] = __builtin_amdgcn_mfma_f32_16x16x32_bf16(af[m], bfr[n], acc[m][n], 0, 0, 0);
            __builtin_amdgcn_s_setprio(0);
        }
        asm volatile("s_waitcnt vmcnt(0)" ::: "memory");   // next tile's loads landed
        __builtin_amdgcn_s_barrier();                      // all waves done reading cur
    }

    const int g = lane >> 4;

    if constexpr (OUTK == 3) {
        // fused invout: out[row,j] += sum_col silu(acc*scale) * w3[col,j] / sqrt(512)
        const float s512f = 0.04419417382415922f;
        float wj0[NF], wj1[NF];
#pragma unroll
        for (int n = 0; n < NF; ++n) {
            int gc = bn + wn * (NF * 16) + n * 16 + rlane;
            wj0[n] = e_w3[gc * 2] * s512f;
            wj1[n] = e_w3[gc * 2 + 1] * s512f;
        }
#pragma unroll
        for (int m = 0; m < 8; ++m)
#pragma unroll
            for (int r = 0; r < 4; ++r) {
                float s0 = 0.f, s1 = 0.f;
#pragma unroll
                for (int n = 0; n < NF; ++n) {
                    float v = acc[m][n][r] * scale;
                    v = v / (1.0f + __expf(-v));
                    s0 = fmaf(v, wj0[n], s0);
                    s1 = fmaf(v, wj1[n], s1);
                }
#pragma unroll
                for (int off = 1; off < 16; off <<= 1) {
                    s0 += __shfl_xor(s0, off);
                    s1 += __shfl_xor(s1, off);
                }
                if (rlane == 0) {
                    int row = bm + wm * 128 + m * 16 + g * 4 + r;
                    atomicAdd(&e_out[row * 2], s0);
                    atomicAdd(&e_out[row * 2 + 1], s1);
                }
            }
    } else {
        // standard epilogue: C/D layout col = lane&15, row = (lane>>4)*4 + reg
#pragma unroll
        for (int m = 0; m < 8; ++m) {
            int grow0 = bm + wm * 128 + m * 16 + (g << 2);
#pragma unroll
            for (int n = 0; n < NF; ++n) {
                int gcol = bn + wn * (NF * 16) + n * 16 + rlane;
#pragma unroll
                for (int r = 0; r < 4; ++r) {
                    float v = acc[m][n][r] * scale;
                    if constexpr (SILU) v = v / (1.0f + __expf(-v));
                    size_t idx = (size_t)(grow0 + r) * ldc + gcol;
                    if constexpr (OUTK == 0) {
                        ((float*)Chi)[idx] = v;
                    } else if constexpr (OUTK == 1) {
                        ((u16*)Chi)[idx] = f2b(v);
                    } else {
                        u16 h = f2b(v);
                        ((u16*)Chi)[idx] = h;
                        ((u16*)Clo)[idx] = f2b(v - b2f(h));
                    }
                }
            }
        }
    }
}

static constexpr float S256 = 0.0625f;                 // 1/sqrt(256)
static constexpr float S512 = 0.04419417382415922f;    // 1/sqrt(512)

// L1 merged (R10-validated): blocks 0-255 = lat (split, NT=12), 256-511 = ro (NT=4)
__global__ void __launch_bounds__(512, 2) gemm_l1(
        const u16* __restrict__ XHI, const u16* __restrict__ XLO,
        const u16* __restrict__ W1LThi, const u16* __restrict__ W1LTlo,
        const u16* __restrict__ W1RT,
        u16* __restrict__ H1Lhi, u16* __restrict__ H1Llo, u16* __restrict__ H1R) {
    __shared__ __align__(16) u16 smem[65536];
    int bid = blockIdx.x;
    if (bid < 256)
        gemm_body<3, 4, true, 2>(smem, XHI, XLO, W1LThi, W1LTlo, H1Lhi, H1Llo,
                                 512, 256, S256, nullptr, nullptr, bid, 256, 2);
    else
        gemm_body<1, 4, true, 1>(smem, XHI, nullptr, W1RT, nullptr, H1R, nullptr,
                                 512, 256, S256, nullptr, nullptr, bid - 256, 256, 2);
}

// lat L2 (separate — R10 showed merging L2 costs ~9us via LDS occupancy)
__global__ void __launch_bounds__(512, 2) gemm_l2lat(
        const u16* __restrict__ H1Lhi, const u16* __restrict__ H1Llo,
        const u16* __restrict__ W2LThi, const u16* __restrict__ W2LTlo,
        u16* __restrict__ H2Lhi, u16* __restrict__ H2Llo) {
    __shared__ __align__(16) u16 smem[65536];
    gemm_body<3, 4, true, 2>(smem, H1Lhi, H1Llo, W2LThi, W2LTlo, H2Lhi, H2Llo,
                             512, 512, S512, nullptr, nullptr, (int)blockIdx.x, 256, 2);
}

// ro L2 + invout fused
__global__ void __launch_bounds__(512, 2) gemm_l2ro(
        const u16* __restrict__ H1R, const u16* __restrict__ W2RT,
        const float* __restrict__ w3r, float* __restrict__ out_inv) {
    __shared__ __align__(16) u16 smem[65536];
    gemm_body<1, 4, true, 3>(smem, H1R, nullptr, W2RT, nullptr, nullptr, nullptr,
                             0, 512, S512, w3r, out_inv, (int)blockIdx.x, 256, 2);
}

// L3 segment-parallel: grid 384 = 3 segments x 128 blocks.  Each segment is a
// plain NSEG=1 bf16 GEMM [32768,512]@[512,128] -> f32 partial WGTp[seg].
// eq_kernel sums the three partials (linear; deterministic, no atomics).
__global__ void __launch_bounds__(512, 1) gemm_l3s(
        const u16* __restrict__ H2Lhi, const u16* __restrict__ H2Llo,
        const u16* __restrict__ W3LThi, const u16* __restrict__ W3LTlo,
        float* __restrict__ WGTp) {
    __shared__ __align__(16) u16 smem[49152];   // 64KB A dbuf + 32KB B dbuf (NF=2)
    int seg = blockIdx.x >> 7;                  // 0..2
    int b = blockIdx.x & 127;
    const u16* A = (seg == 1) ? H2Llo : H2Lhi;
    const u16* B = (seg == 2) ? W3LTlo : W3LThi;
    float* C = WGTp + (size_t)seg * (N_ATOMS * 128);
    gemm_body<1, 2, false, 0>(smem, A, nullptr, B, nullptr, C, nullptr,
                              128, 512, S512, nullptr, nullptr, b, 128, 1);
}

// ---------------- per-atom equivariant output (sums 3 WGT partials) ----------------
__global__ void eq_kernel(const float* __restrict__ eqf, const float* __restrict__ wgt,
                          const int* __restrict__ types, const float* __restrict__ bond,
                          float* __restrict__ out) {
    int t = blockIdx.x * 256 + threadIdx.x;   // 131072 = 32768*4
    int n = t >> 2, v = t & 3;
    const float* e = eqf + (size_t)n * 96;
    const float* w0 = wgt + (size_t)n * 128 + v;
    const float* w1 = w0 + (size_t)N_ATOMS * 128;
    const float* w2 = w1 + (size_t)N_ATOMS * 128;
    float a0 = 0.f, a1 = 0.f, a2 = 0.f;
#pragma unroll
    for (int u = 0; u < 32; ++u) {
        float wv = w0[u * 4] + w1[u * 4] + w2[u * 4];
        a0 = fmaf(e[u * 3 + 0], wv, a0);
        a1 = fmaf(e[u * 3 + 1], wv, a1);
        a2 = fmaf(e[u * 3 + 2], wv, a2);
    }
    const float s = 0.17677669529663687f;   // 1/sqrt(32)
    a0 *= s; a1 *= s; a2 *= s;
    float norm = sqrtf(a0 * a0 + a1 * a1 + a2 * a2) + 1e-10f;
    float bl = bond[types[n] * 4 + v];
    float r0 = a0 / norm, r1 = a1 / norm, r2 = a2 / norm;
    if (isnan(r0)) r0 = 0.f;
    if (isnan(r1)) r1 = 0.f;
    if (isnan(r2)) r2 = 0.f;
    out[(size_t)n * 12 + v * 3 + 0] = r0 * bl;
    out[(size_t)n * 12 + v * 3 + 1] = r1 * bl;
    out[(size_t)n * 12 + v * 3 + 2] = r2 * bl;
}

// ---------------- launcher ----------------
extern "C" void kernel_launch(void* const* d_in, const int* in_sizes, int n_in,
                              void* d_out, int out_size, void* d_ws, size_t ws_size,
                              hipStream_t stream) {
    const float* inv  = (const float*)d_in[0];
    const float* eqf  = (const float*)d_in[1];
    const int*   typs = (const int*)d_in[2];
    const float* w1l  = (const float*)d_in[3];
    const float* w2l  = (const float*)d_in[4];
    const float* w3l  = (const float*)d_in[5];
    const float* w1r  = (const float*)d_in[6];
    const float* w2r  = (const float*)d_in[7];
    const float* w3r  = (const float*)d_in[8];
    const float* bond = (const float*)d_in[9];

    char* ws = (char*)d_ws;
    const size_t MB = 1024 * 1024, KB = 1024;
    // memory map:
    u16* XHI   = (u16*)(ws);             // 16MB, dead after gemm_l1
    u16* XLO   = (u16*)(ws + 16 * MB);   // 16MB, dead after gemm_l1
    u16* H1R   = (u16*)(ws + 32 * MB);   // 32MB, dead after gemm_l2ro
    u16* H1Lhi = (u16*)(ws + 64 * MB);   // 32MB, dead after gemm_l2lat
    u16* H1Llo = (u16*)(ws + 96 * MB);   // 32MB, dead after gemm_l2lat
    u16* H2Lhi = (u16*)(ws);             // 32MB, over XHI+XLO (dead)
    u16* H2Llo = (u16*)(ws + 128 * MB);  // 32MB fresh
    float* WGTp = (float*)(ws + 32 * MB);// 48MB = 3x16MB partials, over H1R+H1Lhi (dead)
    char* wb = ws + 160 * MB;
    u16* W1LThi = (u16*)(wb);
    u16* W1LTlo = (u16*)(wb + 256 * KB);
    u16* W1RT   = (u16*)(wb + 512 * KB);
    u16* W2LThi = (u16*)(wb + 768 * KB);
    u16* W2LTlo = (u16*)(wb + 1280 * KB);
    u16* W2RT   = (u16*)(wb + 1792 * KB);
    u16* W3LThi = (u16*)(wb + 2304 * KB);
    u16* W3LTlo = (u16*)(wb + 2432 * KB);

    float* out_inv = (float*)d_out;                 // [32768][2]
    float* out_eq  = (float*)d_out + N_ATOMS * 2;   // [32768][4][3]

    // 1. setup: convx + convw + zero(out_inv)
    setup_kernel<<<dim3(7488), dim3(256), 0, stream>>>(
        inv, XHI, XLO, w1l, w2l, w3l, w1r, w2r,
        W1LThi, W1LTlo, W1RT, W2LThi, W2LTlo, W2RT, W3LThi, W3LTlo, out_inv);
    // 2. L1 merged: lat (split) -> H1L hi/lo ; ro -> H1R (short blocks backfill)
    gemm_l1<<<dim3(512), dim3(512), 0, stream>>>(
        XHI, XLO, W1LThi, W1LTlo, W1RT, H1Lhi, H1Llo, H1R);
    // 3. ro L2 + invout fused: atomics into out_inv
    gemm_l2ro<<<dim3(256), dim3(512), 0, stream>>>(H1R, W2RT, w3r, out_inv);
    // 4. lat L2 (split): -> H2L hi/lo
    gemm_l2lat<<<dim3(256), dim3(512), 0, stream>>>(
        H1Lhi, H1Llo, W2LThi, W2LTlo, H2Lhi, H2Llo);
    // 5. L3 segment-parallel: 3 partial f32 GEMMs in one dispatch
    gemm_l3s<<<dim3(384), dim3(512), 0, stream>>>(
        H2Lhi, H2Llo, W3LThi, W3LTlo, WGTp);
    // 6. equivariant epilogue (sums partials)
    eq_kernel<<<dim3(512), dim3(256), 0, stream>>>(eqf, WGTp, typs, bond, out_eq);
}

// Round 14
// 186.425 us; speedup vs baseline: 1.1072x; 1.0508x over previous
//
#include <hip/hip_runtime.h>
#include <hip/hip_bf16.h>

#define N_ATOMS 32768

typedef __attribute__((ext_vector_type(4))) float f32x4;
typedef __attribute__((ext_vector_type(8))) short bf16x8;
typedef unsigned short u16;

__device__ __forceinline__ u16 f2b(float f) {
    union { __hip_bfloat16 b; u16 u; } c;
    c.b = __float2bfloat16(f);
    return c.u;
}
__device__ __forceinline__ float b2f(u16 u) {
    union { unsigned int i; float f; } c;
    c.i = ((unsigned int)u) << 16;
    return c.f;
}

#define GLDS16(src, dst) __builtin_amdgcn_global_load_lds( \
    (const __attribute__((address_space(1))) void*)(src),  \
    (__attribute__((address_space(3))) void*)(dst), 16, 0, 0)

// ---------------- merged setup kernel: convx + convw + zero(out_inv) ----------------
__global__ void __launch_bounds__(256) setup_kernel(
        const float* __restrict__ x, u16* __restrict__ xhi, u16* __restrict__ xlo,
        const float* __restrict__ w1l, const float* __restrict__ w2l,
        const float* __restrict__ w3l, const float* __restrict__ w1r,
        const float* __restrict__ w2r,
        u16* __restrict__ W1LThi, u16* __restrict__ W1LTlo, u16* __restrict__ W1RT,
        u16* __restrict__ W2LThi, u16* __restrict__ W2LTlo, u16* __restrict__ W2RT,
        u16* __restrict__ W3LThi, u16* __restrict__ W3LTlo,
        float* __restrict__ out_inv) {
    int bid = blockIdx.x;
    if (bid < 4096) {
        size_t i = (size_t)(bid * 256 + threadIdx.x) * 8;
        float4 v0 = *(const float4*)(x + i);
        float4 v1 = *(const float4*)(x + i + 4);
        float v[8] = {v0.x, v0.y, v0.z, v0.w, v1.x, v1.y, v1.z, v1.w};
        bf16x8 rh, rl;
#pragma unroll
        for (int j = 0; j < 8; ++j) {
            u16 h = f2b(v[j]);
            rh[j] = (short)h;
            rl[j] = (short)f2b(v[j] - b2f(h));
        }
        *(bf16x8*)(xhi + i) = rh;
        *(bf16x8*)(xlo + i) = rl;
    } else if (bid < 7424) {
        int i = (bid - 4096) * 256 + threadIdx.x;
        if (i < 131072) {                       // w1_lat -> [512][256] hi/lo
            int n = i >> 8, k = i & 255;
            float v = w1l[k * 512 + n];
            u16 h = f2b(v);
            W1LThi[i] = h;
            W1LTlo[i] = f2b(v - b2f(h));
        } else if (i < 262144) {                // w1_ro -> [512][256] bf16
            int j = i - 131072;
            int n = j >> 8, k = j & 255;
            W1RT[j] = f2b(w1r[k * 512 + n]);
        } else if (i < 524288) {                // w2_lat -> [512][512] hi/lo
            int j = i - 262144;
            int n = j >> 9, k = j & 511;
            float v = w2l[k * 512 + n];
            u16 h = f2b(v);
            W2LThi[j] = h;
            W2LTlo[j] = f2b(v - b2f(h));
        } else if (i < 786432) {                // w2_ro -> bf16
            int j = i - 524288;
            int n = j >> 9, k = j & 511;
            W2RT[j] = f2b(w2r[k * 512 + n]);
        } else if (i < 851968) {                // w3_lat -> [128][512] hi/lo
            int j = i - 786432;
            int n = j >> 9, k = j & 511;
            float v = w3l[k * 128 + n];
            u16 h = f2b(v);
            W3LThi[j] = h;
            W3LTlo[j] = f2b(v - b2f(h));
        }
    } else {
        int i = (bid - 7424) * 256 + threadIdx.x;
        *(float4*)(out_inv + i * 4) = float4{0.f, 0.f, 0.f, 0.f};
    }
}

// ---------------- 256-row 8-wave MFMA GEMM body (R4/R7/R9/R10-proven schedule) --------
// C = act( scale * sum_seg Aseg @ Bseg^T ).  BM=256, BN=NF*64, BK=64,
// 512 threads = 8 waves (2M x 4N), per-wave 128 x NF*16 output (acc[8][NF]).
// Per K-tile: 2 phases {ds_read frags | stage half of next tile | lgkmcnt(0)
// | setprio(1) MFMA setprio(0)}, then vmcnt(0)+barrier.
// NSEG=3: K-segments (Ahi,Bhi),(Alo,Bhi),(Ahi,Blo) = split-bf16 ~f32 precision.
// OUTK: 0 = f32, 1 = bf16, 2 = split hi/lo bf16,
//       3 = fused invout (dot w3_ro -> atomicAdd e_out, nothing else stored).
template<int NSEG, int NF, bool SILU, int OUTK>
__device__ __forceinline__ void gemm_body(
        u16* __restrict__ smem,
        const u16* __restrict__ Ahi, const u16* __restrict__ Alo,
        const u16* __restrict__ Bhi, const u16* __restrict__ Blo,
        void* __restrict__ Chi, void* __restrict__ Clo,
        int ldc, int K, float scale,
        const float* __restrict__ e_w3, float* __restrict__ e_out,
        int bid, int nwg, int GX) {
    constexpr int LBSZ = NF * 64 * 64;      // u16 per B buffer
    u16* const lA0 = smem;                  // 2 x 16384
    u16* const lB0 = smem + 32768;          // 2 x LBSZ
    const int tid = threadIdx.x;
    const int lane = tid & 63;
    const int wid = tid >> 6;
    const int wm = wid >> 2;            // 0..1 -> 128-row half
    const int wn = wid & 3;             // 0..3 -> NF*16-col quarter
    const int rlane = lane & 15;
    const int kc = lane >> 4;           // 0..3
    const int cps = rlane & 7;
    const int srow = tid >> 3;          // 0..63
    const int scp = tid & 7;

    // bijective XCD swizzle (nwg % 8 == 0)
    const int wg = (bid & 7) * (nwg >> 3) + (bid >> 3);
    const int bn = (wg % GX) * (NF * 64);
    const int bm = (wg / GX) * 256;

    const int kt = K >> 6;
    const int NT = NSEG * kt;

    auto stageA = [&](int t, int buf) {
        int seg = (NSEG == 1) ? 0 : ((t >= kt) + (t >= 2 * kt));
        const u16* As = (NSEG == 1) ? Ahi : (seg == 1 ? Alo : Ahi);
        int k0 = (t - seg * kt) << 6;
        u16* la = lA0 + buf * 16384;
#pragma unroll
        for (int call = 0; call < 4; ++call) {
            int row = call * 64 + srow;
            int c = scp ^ (row & 7);    // pre-swizzled global source, linear LDS dest
            GLDS16(As + (size_t)(bm + row) * K + k0 + c * 8, la + (size_t)(row * 64 + scp * 8));
        }
    };
    auto stageB = [&](int t, int buf) {
        int seg = (NSEG == 1) ? 0 : ((t >= kt) + (t >= 2 * kt));
        const u16* Bs = (NSEG == 1) ? Bhi : (seg == 2 ? Blo : Bhi);
        int k0 = (t - seg * kt) << 6;
        u16* lb = lB0 + buf * LBSZ;
#pragma unroll
        for (int call = 0; call < NF; ++call) {
            int row = call * 64 + srow;
            int c = scp ^ (row & 7);
            GLDS16(Bs + (size_t)(bn + row) * K + k0 + c * 8, lb + (size_t)(row * 64 + scp * 8));
        }
    };

    f32x4 acc[8][NF] = {};

    // prologue: tile 0 in flight, then sync
    stageA(0, 0);
    stageB(0, 0);
    asm volatile("s_waitcnt vmcnt(0)" ::: "memory");
    __builtin_amdgcn_s_barrier();

    for (int t = 0; t < NT; ++t) {
        const int cur = t & 1, nxt = cur ^ 1;
        const bool pf = (t + 1 < NT);
        const u16* la = lA0 + cur * 16384;
        const u16* lb = lB0 + cur * LBSZ;
#pragma unroll
        for (int ks = 0; ks < 2; ++ks) {
            bf16x8 af[8], bfr[NF];
            const int cp = (ks * 4 + kc) ^ cps;
#pragma unroll
            for (int m = 0; m < 8; ++m) {
                int row = wm * 128 + m * 16 + rlane;
                af[m] = *(const bf16x8*)&la[row * 64 + cp * 8];
            }
#pragma unroll
            for (int n = 0; n < NF; ++n) {
                int row = wn * (NF * 16) + n * 16 + rlane;
                bfr[n] = *(const bf16x8*)&lb[row * 64 + cp * 8];
            }
            if (pf) {                       // issue next tile's loads early (stay in flight)
                if (ks == 0) stageA(t + 1, nxt);
                else         stageB(t + 1, nxt);
            }
            asm volatile("s_waitcnt lgkmcnt(0)" ::: "memory");
            __builtin_amdgcn_sched_barrier(0);
            __builtin_amdgcn_s_setprio(1);
#pragma unroll
            for (int m = 0; m < 8; ++m)
#pragma unroll
                for (int n = 0; n < NF; ++n)
                    acc[m][n] = __builtin_amdgcn_mfma_f32_16x16x32_bf16(af[m], bfr[n], acc[m][n], 0, 0, 0);
            __builtin_amdgcn_s_setprio(0);
        }
        asm volatile("s_waitcnt vmcnt(0)" ::: "memory");   // next tile's loads landed
        __builtin_amdgcn_s_barrier();                      // all waves done reading cur
    }

    const int g = lane >> 4;

    if constexpr (OUTK == 3) {
        // fused invout: out[row,j] += sum_col silu(acc*scale) * w3[col,j] / sqrt(512)
        const float s512f = 0.04419417382415922f;
        float wj0[NF], wj1[NF];
#pragma unroll
        for (int n = 0; n < NF; ++n) {
            int gc = bn + wn * (NF * 16) + n * 16 + rlane;
            wj0[n] = e_w3[gc * 2] * s512f;
            wj1[n] = e_w3[gc * 2 + 1] * s512f;
        }
#pragma unroll
        for (int m = 0; m < 8; ++m)
#pragma unroll
            for (int r = 0; r < 4; ++r) {
                float s0 = 0.f, s1 = 0.f;
#pragma unroll
                for (int n = 0; n < NF; ++n) {
                    float v = acc[m][n][r] * scale;
                    v = v / (1.0f + __expf(-v));
                    s0 = fmaf(v, wj0[n], s0);
                    s1 = fmaf(v, wj1[n], s1);
                }
#pragma unroll
                for (int off = 1; off < 16; off <<= 1) {
                    s0 += __shfl_xor(s0, off);
                    s1 += __shfl_xor(s1, off);
                }
                if (rlane == 0) {
                    int row = bm + wm * 128 + m * 16 + g * 4 + r;
                    atomicAdd(&e_out[row * 2], s0);
                    atomicAdd(&e_out[row * 2 + 1], s1);
                }
            }
    } else {
        // standard epilogue: C/D layout col = lane&15, row = (lane>>4)*4 + reg
#pragma unroll
        for (int m = 0; m < 8; ++m) {
            int grow0 = bm + wm * 128 + m * 16 + (g << 2);
#pragma unroll
            for (int n = 0; n < NF; ++n) {
                int gcol = bn + wn * (NF * 16) + n * 16 + rlane;
#pragma unroll
                for (int r = 0; r < 4; ++r) {
                    float v = acc[m][n][r] * scale;
                    if constexpr (SILU) v = v / (1.0f + __expf(-v));
                    size_t idx = (size_t)(grow0 + r) * ldc + gcol;
                    if constexpr (OUTK == 0) {
                        ((float*)Chi)[idx] = v;
                    } else if constexpr (OUTK == 1) {
                        ((u16*)Chi)[idx] = f2b(v);
                    } else {
                        u16 h = f2b(v);
                        ((u16*)Chi)[idx] = h;
                        ((u16*)Clo)[idx] = f2b(v - b2f(h));
                    }
                }
            }
        }
    }
}

static constexpr float S256 = 0.0625f;                 // 1/sqrt(256)
static constexpr float S512 = 0.04419417382415922f;    // 1/sqrt(512)

// L1 merged (R10/R13): blocks 0-255 = lat (split, NT=12), 256-511 = ro (NT=4)
__global__ void __launch_bounds__(512, 2) gemm_l1(
        const u16* __restrict__ XHI, const u16* __restrict__ XLO,
        const u16* __restrict__ W1LThi, const u16* __restrict__ W1LTlo,
        const u16* __restrict__ W1RT,
        u16* __restrict__ H1Lhi, u16* __restrict__ H1Llo, u16* __restrict__ H1R) {
    __shared__ __align__(16) u16 smem[65536];
    int bid = blockIdx.x;
    if (bid < 256)
        gemm_body<3, 4, true, 2>(smem, XHI, XLO, W1LThi, W1LTlo, H1Lhi, H1Llo,
                                 512, 256, S256, nullptr, nullptr, bid, 256, 2);
    else
        gemm_body<1, 4, true, 1>(smem, XHI, nullptr, W1RT, nullptr, H1R, nullptr,
                                 512, 256, S256, nullptr, nullptr, bid - 256, 256, 2);
}

// lat L2 separate (R13-validated: merging L2 costs ~10us via LDS occupancy)
__global__ void __launch_bounds__(512, 2) gemm_l2lat(
        const u16* __restrict__ H1Lhi, const u16* __restrict__ H1Llo,
        const u16* __restrict__ W2LThi, const u16* __restrict__ W2LTlo,
        u16* __restrict__ H2Lhi, u16* __restrict__ H2Llo) {
    __shared__ __align__(16) u16 smem[65536];
    gemm_body<3, 4, true, 2>(smem, H1Lhi, H1Llo, W2LThi, W2LTlo, H2Lhi, H2Llo,
                             512, 512, S512, nullptr, nullptr, (int)blockIdx.x, 256, 2);
}

// ro L2 + invout fused
__global__ void __launch_bounds__(512, 2) gemm_l2ro(
        const u16* __restrict__ H1R, const u16* __restrict__ W2RT,
        const float* __restrict__ w3r, float* __restrict__ out_inv) {
    __shared__ __align__(16) u16 smem[65536];
    gemm_body<1, 4, true, 3>(smem, H1R, nullptr, W2RT, nullptr, nullptr, nullptr,
                             0, 512, S512, w3r, out_inv, (int)blockIdx.x, 256, 2);
}

// L3 (R10-validated): gemm8p NF=1, GX=2 -> grid 256 (full GPU), 80KB LDS.
__global__ void __launch_bounds__(512, 2) gemm_l3(
        const u16* __restrict__ H2Lhi, const u16* __restrict__ H2Llo,
        const u16* __restrict__ W3LThi, const u16* __restrict__ W3LTlo,
        float* __restrict__ WGT) {
    __shared__ __align__(16) u16 smem[40960];   // 64KB A dbuf + 16KB B dbuf (NF=1)
    gemm_body<3, 1, false, 0>(smem, H2Lhi, H2Llo, W3LThi, W3LTlo, WGT, nullptr,
                              128, 512, S512, nullptr, nullptr, (int)blockIdx.x, 256, 2);
}

// ---------------- per-atom equivariant output (R2/R9-verified) ----------------
__global__ void eq_kernel(const float* __restrict__ eqf, const float* __restrict__ wgt,
                          const int* __restrict__ types, const float* __restrict__ bond,
                          float* __restrict__ out) {
    int t = blockIdx.x * 256 + threadIdx.x;   // 131072 = 32768*4
    int n = t >> 2, v = t & 3;
    const float* e = eqf + (size_t)n * 96;
    const float* w = wgt + (size_t)n * 128 + v;
    float a0 = 0.f, a1 = 0.f, a2 = 0.f;
#pragma unroll
    for (int u = 0; u < 32; ++u) {
        float wv = w[u * 4];
        a0 = fmaf(e[u * 3 + 0], wv, a0);
        a1 = fmaf(e[u * 3 + 1], wv, a1);
        a2 = fmaf(e[u * 3 + 2], wv, a2);
    }
    const float s = 0.17677669529663687f;   // 1/sqrt(32)
    a0 *= s; a1 *= s; a2 *= s;
    float norm = sqrtf(a0 * a0 + a1 * a1 + a2 * a2) + 1e-10f;
    float bl = bond[types[n] * 4 + v];
    float r0 = a0 / norm, r1 = a1 / norm, r2 = a2 / norm;
    if (isnan(r0)) r0 = 0.f;
    if (isnan(r1)) r1 = 0.f;
    if (isnan(r2)) r2 = 0.f;
    out[(size_t)n * 12 + v * 3 + 0] = r0 * bl;
    out[(size_t)n * 12 + v * 3 + 1] = r1 * bl;
    out[(size_t)n * 12 + v * 3 + 2] = r2 * bl;
}

// ---------------- launcher ----------------
extern "C" void kernel_launch(void* const* d_in, const int* in_sizes, int n_in,
                              void* d_out, int out_size, void* d_ws, size_t ws_size,
                              hipStream_t stream) {
    const float* inv  = (const float*)d_in[0];
    const float* eqf  = (const float*)d_in[1];
    const int*   typs = (const int*)d_in[2];
    const float* w1l  = (const float*)d_in[3];
    const float* w2l  = (const float*)d_in[4];
    const float* w3l  = (const float*)d_in[5];
    const float* w1r  = (const float*)d_in[6];
    const float* w2r  = (const float*)d_in[7];
    const float* w3r  = (const float*)d_in[8];
    const float* bond = (const float*)d_in[9];

    char* ws = (char*)d_ws;
    const size_t MB = 1024 * 1024, KB = 1024;
    // memory map:
    u16* XHI   = (u16*)(ws);             // 16MB, dead after gemm_l1
    u16* XLO   = (u16*)(ws + 16 * MB);   // 16MB, dead after gemm_l1
    u16* H1R   = (u16*)(ws + 32 * MB);   // 32MB, dead after gemm_l2ro
    u16* H1Lhi = (u16*)(ws + 64 * MB);   // 32MB, dead after gemm_l2lat
    u16* H1Llo = (u16*)(ws + 96 * MB);   // 32MB, dead after gemm_l2lat
    u16* H2Lhi = (u16*)(ws);             // 32MB, over XHI+XLO (dead)
    u16* H2Llo = (u16*)(ws + 128 * MB);  // 32MB fresh
    float* WGT = (float*)(ws + 32 * MB); // 16MB, over H1R (dead when gemm_l3 runs)
    char* wb = ws + 160 * MB;
    u16* W1LThi = (u16*)(wb);
    u16* W1LTlo = (u16*)(wb + 256 * KB);
    u16* W1RT   = (u16*)(wb + 512 * KB);
    u16* W2LThi = (u16*)(wb + 768 * KB);
    u16* W2LTlo = (u16*)(wb + 1280 * KB);
    u16* W2RT   = (u16*)(wb + 1792 * KB);
    u16* W3LThi = (u16*)(wb + 2304 * KB);
    u16* W3LTlo = (u16*)(wb + 2432 * KB);

    float* out_inv = (float*)d_out;                 // [32768][2]
    float* out_eq  = (float*)d_out + N_ATOMS * 2;   // [32768][4][3]

    // 1. setup: convx + convw + zero(out_inv)
    setup_kernel<<<dim3(7488), dim3(256), 0, stream>>>(
        inv, XHI, XLO, w1l, w2l, w3l, w1r, w2r,
        W1LThi, W1LTlo, W1RT, W2LThi, W2LTlo, W2RT, W3LThi, W3LTlo, out_inv);
    // 2. L1 merged: lat (split) -> H1L hi/lo ; ro -> H1R
    gemm_l1<<<dim3(512), dim3(512), 0, stream>>>(
        XHI, XLO, W1LThi, W1LTlo, W1RT, H1Lhi, H1Llo, H1R);
    // 3. ro L2 + invout fused: atomics into out_inv
    gemm_l2ro<<<dim3(256), dim3(512), 0, stream>>>(H1R, W2RT, w3r, out_inv);
    // 4. lat L2 (split): -> H2L hi/lo
    gemm_l2lat<<<dim3(256), dim3(512), 0, stream>>>(
        H1Lhi, H1Llo, W2LThi, W2LTlo, H2Lhi, H2Llo);
    // 5. L3 (R10-validated gemm8p NF=1): -> WGT f32
    gemm_l3<<<dim3(256), dim3(512), 0, stream>>>(
        H2Lhi, H2Llo, W3LThi, W3LTlo, WGT);
    // 6. equivariant epilogue
    eq_kernel<<<dim3(512), dim3(256), 0, stream>>>(eqf, WGT, typs, bond, out_eq);
}